// Round 9
// baseline (88.921 us; speedup 1.0000x reference)
//
#include <hip/hip_runtime.h>
#include <cstdint>
#include <cstddef>

// ---------------------------------------------------------------------------
// B=4, N=1024, C=256, H=8, hd=32, ALPHA=0.6
// softmax rows sum to 1 => S_x = attn_x^T; associativity kills the N^3 work.
// r9: dual-frag waves (r8 math, proven) at 256-thr / 4-wave blocks, grid
// (64,8), ~72.7KB LDS => 2 independent blocks/CU (r8 regressed because its
// 512-thr/95KB config left 1 block/CU: barrier phases idled the whole CU).
// Shared K/V/Q/O fragment reads feed 2 MFMAs each => ~1.8x less LDS issue
// per unit work than r6.
// ---------------------------------------------------------------------------

typedef _Float16 f16;
typedef _Float16 half8 __attribute__((ext_vector_type(8)));
typedef float f32x4 __attribute__((ext_vector_type(4)));

#define ALPHA_F 0.6f
#define OMA_F   0.4f
#define SCALE_L2E 0.25503482f  // (1/sqrt(32)) * log2(e)

static const size_t WS_QKVH = 0;               // 8192*768*2   = 12,582,912
static const size_t WS_VT   = 12582912ull;     // 32*64*1024*2 =  4,194,304
static const size_t WS_OT   = 16777216ull;     // 64*64*1024*2 =  8,388,608
static const size_t WS_RS   = 25165824ull;     // 64*1024*4    =    262,144

__device__ __forceinline__ uint4 pack8(float4 a, float4 b) {
  union { f16 h[8]; uint4 u; } pk;
  pk.h[0] = (f16)a.x; pk.h[1] = (f16)a.y; pk.h[2] = (f16)a.z; pk.h[3] = (f16)a.w;
  pk.h[4] = (f16)b.x; pk.h[5] = (f16)b.y; pk.h[6] = (f16)b.z; pk.h[7] = (f16)b.w;
  return pk.u;
}

// ---------------------------------------------------------------------------
// K1: proj MFMA GEMM, LDS-staged, f32 inputs cast in staging (unchanged).
__global__ __launch_bounds__(512) void k_projm(const float* __restrict__ x,
                                               const float* __restrict__ wr,
                                               const float* __restrict__ wd,
                                               f16* __restrict__ qkvh,
                                               f16* __restrict__ VT) {
  __shared__ f16 Ws[64][264];
  __shared__ f16 Xs[2][128][40];
  __shared__ f16 sc[8][64][24];
  const int t = threadIdx.x;
  const int w = t >> 6, l = t & 63, g = l >> 4, li = l & 15;
  const int m0 = blockIdx.x * 128;
  const int j0 = blockIdx.y * 64;
  const int br = m0 >> 12;
  const int mrow = m0 & 4095;
  const bool qk = (j0 < 512);
  const float* wsrc = br ? wd : wr;
#pragma unroll
  for (int ps = 0; ps < 4; ++ps) {
    const int idx = ps * 512 + t;
    const int wrow = idx >> 5, wc8 = (idx & 31) * 8;
    const float* s = wsrc + (size_t)(j0 + wrow) * 256 + wc8;
    *(uint4*)&Ws[wrow][wc8] = pack8(*(const float4*)s, *(const float4*)(s + 4));
  }
  const int xrow = t >> 2, xc8 = (t & 3) * 8;
  const float* xgl = x + (size_t)(mrow + xrow) * 512 + br * 256 + xc8;
  float4 xr0 = *(const float4*)xgl;
  float4 xr1 = *(const float4*)(xgl + 4);
  *(uint4*)&Xs[0][xrow][xc8] = pack8(xr0, xr1);
  const f32x4 z = {0.f, 0.f, 0.f, 0.f};
  f32x4 c[4] = {z, z, z, z};
  int cur = 0;
  for (int kc = 0; kc < 8; ++kc, cur ^= 1) {
    __syncthreads();
    if (kc < 7) {
      xr0 = *(const float4*)(xgl + (kc + 1) * 32);
      xr1 = *(const float4*)(xgl + (kc + 1) * 32 + 4);
    }
    half8 xa = *(const half8*)&Xs[cur][w * 16 + li][8 * g];
    if (qk) {
#pragma unroll
      for (int jf = 0; jf < 4; ++jf) {
        half8 wa = *(const half8*)&Ws[jf * 16 + li][kc * 32 + 8 * g];
        c[jf] = __builtin_amdgcn_mfma_f32_16x16x32_f16(wa, xa, c[jf], 0, 0, 0);
      }
    } else {
#pragma unroll
      for (int jf = 0; jf < 4; ++jf) {
        half8 wa = *(const half8*)&Ws[jf * 16 + li][kc * 32 + 8 * g];
        c[jf] = __builtin_amdgcn_mfma_f32_16x16x32_f16(xa, wa, c[jf], 0, 0, 0);
      }
    }
    if (kc < 7) *(uint4*)&Xs[cur ^ 1][xrow][xc8] = pack8(xr0, xr1);
  }
  if (qk) {
    f16 (*Qw)[72] = (f16(*)[72])&sc[w][0][0];
#pragma unroll
    for (int jf = 0; jf < 4; ++jf) {
      union { f16 h[4]; uint2 u; } pk;
#pragma unroll
      for (int r = 0; r < 4; ++r) pk.h[r] = (f16)c[jf][r];
      *(uint2*)&Qw[li][jf * 16 + 4 * g] = pk.u;
    }
    const int n = l >> 2, jc = (l & 3) * 16;
    uint4 v0 = *(const uint4*)&Qw[n][jc];
    uint4 v1 = *(const uint4*)&Qw[n][jc + 8];
    f16* dst = qkvh + (size_t)(m0 + w * 16 + n) * 768 + j0 + jc;
    *(uint4*)dst = v0;
    *(uint4*)(dst + 8) = v1;
  } else {
    f16 (*Vw)[24] = (f16(*)[24])&sc[w][0][0];
#pragma unroll
    for (int jf = 0; jf < 4; ++jf) {
      union { f16 h[4]; uint2 u; } pk;
#pragma unroll
      for (int r = 0; r < 4; ++r) pk.h[r] = (f16)c[jf][r];
      *(uint2*)&Vw[jf * 16 + li][4 * g] = pk.u;
    }
    const int jg = j0 + l - 512;
    const int hh = jg >> 5, dd = jg & 31;
    const int b = mrow >> 10;
    const int nn = (mrow & 1023) + w * 16;
    uint4 v0 = *(const uint4*)&Vw[l][0];
    uint4 v1 = *(const uint4*)&Vw[l][8];
    f16* dst = VT + ((size_t)(b * 8 + hh) * 64 + br * 32 + dd) * 1024 + nn;
    *(uint4*)dst = v0;
    *(uint4*)(dst + 8) = v1;
  }
}

// ---------------------------------------------------------------------------
// K2: fused flash pass, dual q-frag waves (32 q/wave), 4 waves/block,
// grid (64,8) = 512 blocks, 2 blocks/CU.
__global__ __launch_bounds__(256) void k_fused1(const f16* __restrict__ qkvh,
                                                const f16* __restrict__ VT,
                                                f16* __restrict__ OT,
                                                float* __restrict__ rsums,
                                                float* __restrict__ out) {
  __shared__ f16 Ks[2][128][32];    // 16384 B
  __shared__ f16 Vs[2][64][136];    // 34816 B
  __shared__ f16 scw[4][2624];      // 20992 B: P0[16][68]|P1[16][68]; reuse Ow[64][40]
  __shared__ float rsh[4][32];
  const int t = threadIdx.x;
  const int bb = blockIdx.x;
  const int br = bb >> 5, bh = bb & 31, b = bh >> 3, h = bh & 7;
  const int w = t >> 6, l = t & 63, g = l >> 4, li = l & 15;
  const int q0 = blockIdx.y * 128 + w * 32;
  const size_t rowbase = (size_t)(br * 4096 + b * 1024) * 768;
  half8 qf0 = *(const half8*)(qkvh + rowbase + (size_t)(q0 + li) * 768 + h * 32 + 8 * g);
  half8 qf1 = *(const half8*)(qkvh + rowbase + (size_t)(q0 + 16 + li) * 768 + h * 32 + 8 * g);
  // staging (256 thr): K 128x32 -> 2 uint4/thr; V 64x128 -> 4 uint4/thr
  const int krow = t >> 1, kc16 = (t & 1) * 16;
  const int vrow = t >> 2, vc8 = (t & 3) * 8;
  const f16* kgl = qkvh + rowbase + (size_t)krow * 768 + 256 + h * 32 + kc16;
  const f16* vgl = VT + ((size_t)bh * 64 + vrow) * 1024 + vc8;
  uint4 kr0 = *(const uint4*)kgl;
  uint4 kr1 = *(const uint4*)(kgl + 8);
  uint4 vr0 = *(const uint4*)vgl;
  uint4 vr1 = *(const uint4*)(vgl + 32);
  uint4 vr2 = *(const uint4*)(vgl + 64);
  uint4 vr3 = *(const uint4*)(vgl + 96);
  *(uint4*)&Ks[0][krow][kc16] = kr0;
  *(uint4*)&Ks[0][krow][kc16 + 8] = kr1;
  *(uint4*)&Vs[0][vrow][vc8] = vr0;
  *(uint4*)&Vs[0][vrow][vc8 + 32] = vr1;
  *(uint4*)&Vs[0][vrow][vc8 + 64] = vr2;
  *(uint4*)&Vs[0][vrow][vc8 + 96] = vr3;
  f16 (*P0)[68] = (f16(*)[68])&scw[w][0];
  f16 (*P1)[68] = (f16(*)[68])&scw[w][1088];
  const f32x4 z = {0.f, 0.f, 0.f, 0.f};
  f32x4 o0[4] = {z, z, z, z};
  f32x4 o1[4] = {z, z, z, z};
  float qsum0 = 0.f, qsum1 = 0.f;
  int cur = 0;
  for (int tile = 0; tile < 8; ++tile, cur ^= 1) {
    __syncthreads();
    if (tile < 7) {
      const int m1 = (tile + 1) * 128;
      kr0 = *(const uint4*)(kgl + (size_t)m1 * 768);
      kr1 = *(const uint4*)(kgl + (size_t)m1 * 768 + 8);
      vr0 = *(const uint4*)(vgl + m1);
      vr1 = *(const uint4*)(vgl + m1 + 32);
      vr2 = *(const uint4*)(vgl + m1 + 64);
      vr3 = *(const uint4*)(vgl + m1 + 96);
    }
#pragma unroll
    for (int kh = 0; kh < 2; ++kh) {
      f32x4 s0[4], s1[4];
#pragma unroll
      for (int ct = 0; ct < 4; ++ct) {
        half8 ka = *(const half8*)&Ks[cur][kh * 64 + ct * 16 + li][8 * g];
        s0[ct] = __builtin_amdgcn_mfma_f32_16x16x32_f16(ka, qf0, z, 0, 0, 0);
        s1[ct] = __builtin_amdgcn_mfma_f32_16x16x32_f16(ka, qf1, z, 0, 0, 0);
      }
#pragma unroll
      for (int ct = 0; ct < 4; ++ct) {
        union { f16 hh[4]; uint2 u; } pk0, pk1;
#pragma unroll
        for (int r = 0; r < 4; ++r) {
          float p0 = exp2f(s0[ct][r] * SCALE_L2E);
          float p1 = exp2f(s1[ct][r] * SCALE_L2E);
          qsum0 += p0; qsum1 += p1;
          pk0.hh[r] = (f16)p0; pk1.hh[r] = (f16)p1;
        }
        *(uint2*)&P0[li][ct * 16 + 4 * g] = pk0.u;
        *(uint2*)&P1[li][ct * 16 + 4 * g] = pk1.u;
      }
#pragma unroll
      for (int kk = 0; kk < 2; ++kk) {
        half8 pa0 = *(const half8*)&P0[li][kk * 32 + 8 * g];
        half8 pa1 = *(const half8*)&P1[li][kk * 32 + 8 * g];
#pragma unroll
        for (int jf = 0; jf < 4; ++jf) {
          half8 vv = *(const half8*)&Vs[cur][jf * 16 + li][kh * 64 + kk * 32 + 8 * g];
          o0[jf] = __builtin_amdgcn_mfma_f32_16x16x32_f16(pa0, vv, o0[jf], 0, 0, 0);
          o1[jf] = __builtin_amdgcn_mfma_f32_16x16x32_f16(pa1, vv, o1[jf], 0, 0, 0);
        }
      }
    }
    if (tile < 7) {
      *(uint4*)&Ks[cur ^ 1][krow][kc16] = kr0;
      *(uint4*)&Ks[cur ^ 1][krow][kc16 + 8] = kr1;
      *(uint4*)&Vs[cur ^ 1][vrow][vc8] = vr0;
      *(uint4*)&Vs[cur ^ 1][vrow][vc8 + 32] = vr1;
      *(uint4*)&Vs[cur ^ 1][vrow][vc8 + 64] = vr2;
      *(uint4*)&Vs[cur ^ 1][vrow][vc8 + 96] = vr3;
    }
  }
  qsum0 += __shfl_xor(qsum0, 16, 64);
  qsum0 += __shfl_xor(qsum0, 32, 64);
  qsum1 += __shfl_xor(qsum1, 16, 64);
  qsum1 += __shfl_xor(qsum1, 32, 64);
  const float rinv0 = 1.0f / qsum0;
  const float rinv1 = 1.0f / qsum1;
  if (l < 16) {
    rsh[w][li] = rinv0;
    rsh[w][16 + li] = rinv1;
    rsums[(size_t)bb * 1024 + q0 + li] = rinv0;
    rsums[(size_t)bb * 1024 + q0 + 16 + li] = rinv1;
  }
  float rv0[4], rv1[4];
#pragma unroll
  for (int r = 0; r < 4; ++r) {
    rv0[r] = rsh[w][4 * g + r];
    rv1[r] = rsh[w][16 + 4 * g + r];
  }
#pragma unroll
  for (int jf = 0; jf < 4; ++jf)
#pragma unroll
    for (int r = 0; r < 4; ++r) {
      o0[jf][r] *= rv0[r];
      o1[jf][r] *= rv1[r];
    }
  // ---- out_r / out_d straight from registers (both frags) ----
  {
    const int jf0 = br * 2;
    float* ob0 = out + ((size_t)((2 + br) * 4 + b) * 1024 + q0 + 4 * g) * 256 + h * 32 + li;
    float* ob1 = out + ((size_t)((2 + br) * 4 + b) * 1024 + q0 + 16 + 4 * g) * 256 + h * 32 + li;
#pragma unroll
    for (int jf2 = 0; jf2 < 2; ++jf2)
#pragma unroll
      for (int r = 0; r < 4; ++r) {
        ob0[(size_t)r * 256 + jf2 * 16] = o0[jf0 + jf2][r];
        ob1[(size_t)r * 256 + jf2 * 16] = o1[jf0 + jf2][r];
      }
  }
  // ---- transpose O (32q x 64j) -> Ow[j][q] rows [64][40], then OT ----
  f16 (*Ow)[40] = (f16(*)[40])&scw[w][0];
#pragma unroll
  for (int jf = 0; jf < 4; ++jf)
#pragma unroll
    for (int rp = 0; rp < 2; ++rp) {
      union { f16 h[2]; unsigned int u; } a0, a1;
      a0.h[0] = (f16)o0[jf][2 * rp]; a0.h[1] = (f16)o0[jf][2 * rp + 1];
      a1.h[0] = (f16)o1[jf][2 * rp]; a1.h[1] = (f16)o1[jf][2 * rp + 1];
      *(unsigned int*)&Ow[jf * 16 + li][4 * g + 2 * rp] = a0.u;
      *(unsigned int*)&Ow[jf * 16 + li][16 + 4 * g + 2 * rp] = a1.u;
    }
  {
    f16* dst = OT + ((size_t)bb * 64 + l) * 1024 + q0;
    uint4 v0 = *(const uint4*)&Ow[l][0];
    uint4 v1 = *(const uint4*)&Ow[l][8];
    uint4 v2 = *(const uint4*)&Ow[l][16];
    uint4 v3 = *(const uint4*)&Ow[l][24];
    *(uint4*)dst = v0;
    *(uint4*)(dst + 8) = v1;
    *(uint4*)(dst + 16) = v2;
    *(uint4*)(dst + 24) = v3;
  }
}

// ---------------------------------------------------------------------------
// K3: fused recompute + U + combine, dual n-frag waves (32 n/wave),
// 4 waves/block, grid (64,8) = 512 blocks, 2 blocks/CU.
__global__ __launch_bounds__(256) void k_fused2(const f16* __restrict__ qkvh,
                                                const f16* __restrict__ OT,
                                                const float* __restrict__ rsums,
                                                float* __restrict__ out) {
  __shared__ f16 Qs[2][128][32];    // 16384 B
  __shared__ f16 Os[2][32][136];    // 17408 B
  __shared__ f16 sc2h[4][4352];     // 34816 B: P0[16][136]|P1[16][136]; reuse Uw0/Uw1
  __shared__ float rb[1024];
  const int t = threadIdx.x;
  const int pb = blockIdx.x;
  const int p = pb >> 5, bh = pb & 31, b = bh >> 3, h = bh & 7;
  const int w = t >> 6, l = t & 63, g = l >> 4, li = l & 15;
  const int n0 = blockIdx.y * 128 + w * 32;
  const int abb = p * 32 + bh;
  const int obb = p ? bh : 32 + bh;
  const int aoff = p ? 0 : 32;
  const size_t rowbase = (size_t)(p * 4096 + b * 1024) * 768;
  rb[t] = rsums[(size_t)abb * 1024 + t];
  rb[t + 256] = rsums[(size_t)abb * 1024 + t + 256];
  rb[t + 512] = rsums[(size_t)abb * 1024 + t + 512];
  rb[t + 768] = rsums[(size_t)abb * 1024 + t + 768];
  half8 kf0 = *(const half8*)(qkvh + rowbase + (size_t)(n0 + li) * 768 + 256 + h * 32 + 8 * g);
  half8 kf1 = *(const half8*)(qkvh + rowbase + (size_t)(n0 + 16 + li) * 768 + 256 + h * 32 + 8 * g);
  // staging (256 thr): Q 128x32 -> 2 uint4/thr; O 32x128 -> 2 uint4/thr
  const int qrow = t >> 1, qc16 = (t & 1) * 16;
  const int orow = t >> 3, oc16 = (t & 7) * 16;
  const f16* qgl = qkvh + rowbase + (size_t)qrow * 768 + h * 32 + qc16;
  const f16* ogl = OT + ((size_t)obb * 64 + aoff + orow) * 1024 + oc16;
  uint4 qr0 = *(const uint4*)qgl;
  uint4 qr1 = *(const uint4*)(qgl + 8);
  uint4 or0 = *(const uint4*)ogl;
  uint4 or1 = *(const uint4*)(ogl + 8);
  *(uint4*)&Qs[0][qrow][qc16] = qr0;
  *(uint4*)&Qs[0][qrow][qc16 + 8] = qr1;
  *(uint4*)&Os[0][orow][oc16] = or0;
  *(uint4*)&Os[0][orow][oc16 + 8] = or1;
  f16 (*P0)[136] = (f16(*)[136])&sc2h[w][0];
  f16 (*P1)[136] = (f16(*)[136])&sc2h[w][2176];
  const f32x4 z = {0.f, 0.f, 0.f, 0.f};
  f32x4 u00 = z, u01 = z, u10 = z, u11 = z;
  int cur = 0;
  for (int tile = 0; tile < 8; ++tile, cur ^= 1) {
    __syncthreads();
    if (tile < 7) {
      const int q1 = (tile + 1) * 128;
      qr0 = *(const uint4*)(qgl + (size_t)q1 * 768);
      qr1 = *(const uint4*)(qgl + (size_t)q1 * 768 + 8);
      or0 = *(const uint4*)(ogl + q1);
      or1 = *(const uint4*)(ogl + q1 + 8);
    }
    const int qt0 = tile * 128;
#pragma unroll
    for (int fq = 0; fq < 8; ++fq) {
      half8 qa = *(const half8*)&Qs[cur][fq * 16 + li][8 * g];
      f32x4 s0 = __builtin_amdgcn_mfma_f32_16x16x32_f16(qa, kf0, z, 0, 0, 0);
      f32x4 s1 = __builtin_amdgcn_mfma_f32_16x16x32_f16(qa, kf1, z, 0, 0, 0);
      union { f16 hh[4]; uint2 u; } pk0, pk1;
#pragma unroll
      for (int r = 0; r < 4; ++r) {
        const float rr = rb[qt0 + fq * 16 + 4 * g + r];
        pk0.hh[r] = (f16)(exp2f(s0[r] * SCALE_L2E) * rr);
        pk1.hh[r] = (f16)(exp2f(s1[r] * SCALE_L2E) * rr);
      }
      *(uint2*)&P0[li][fq * 16 + 4 * g] = pk0.u;
      *(uint2*)&P1[li][fq * 16 + 4 * g] = pk1.u;
    }
#pragma unroll
    for (int kk = 0; kk < 4; ++kk) {
      half8 pb0 = *(const half8*)&P0[li][kk * 32 + 8 * g];
      half8 pb1 = *(const half8*)&P1[li][kk * 32 + 8 * g];
      half8 A0 = *(const half8*)&Os[cur][li][kk * 32 + 8 * g];
      half8 A1 = *(const half8*)&Os[cur][16 + li][kk * 32 + 8 * g];
      u00 = __builtin_amdgcn_mfma_f32_16x16x32_f16(A0, pb0, u00, 0, 0, 0);
      u01 = __builtin_amdgcn_mfma_f32_16x16x32_f16(A1, pb0, u01, 0, 0, 0);
      u10 = __builtin_amdgcn_mfma_f32_16x16x32_f16(A0, pb1, u10, 0, 0, 0);
      u11 = __builtin_amdgcn_mfma_f32_16x16x32_f16(A1, pb1, u11, 0, 0, 0);
    }
    if (tile < 7) {
      *(uint4*)&Qs[cur ^ 1][qrow][qc16] = qr0;
      *(uint4*)&Qs[cur ^ 1][qrow][qc16 + 8] = qr1;
      *(uint4*)&Os[cur ^ 1][orow][oc16] = or0;
      *(uint4*)&Os[cur ^ 1][orow][oc16 + 8] = or1;
    }
  }
  // combine: alpha*U + 0.4*(OT[bh] + OT[32+bh]) rows aoff+d  (both frags)
  float (*Uw0)[36] = (float(*)[36])&sc2h[w][0];
  float (*Uw1)[36] = (float(*)[36])&sc2h[w][2176];
#pragma unroll
  for (int df = 0; df < 2; ++df)
#pragma unroll
    for (int r = 0; r < 4; ++r) {
      const int d_l = df * 16 + 4 * g + r;
      const size_t rowr = ((size_t)bh * 64 + aoff + d_l) * 1024;
      const size_t rowd = ((size_t)(32 + bh) * 64 + aoff + d_l) * 1024;
      float uu0 = df ? u01[r] : u00[r];
      float uu1 = df ? u11[r] : u10[r];
      float a10 = (float)OT[rowr + n0 + li];
      float a20 = (float)OT[rowd + n0 + li];
      float a11 = (float)OT[rowr + n0 + 16 + li];
      float a21 = (float)OT[rowd + n0 + 16 + li];
      Uw0[li][d_l] = ALPHA_F * uu0 + OMA_F * (a10 + a20);
      Uw1[li][d_l] = ALPHA_F * uu1 + OMA_F * (a11 + a21);
    }
  const int nn = l >> 2, dq = (l & 3) * 8;
  {
    f32x4 v0 = *(const f32x4*)&Uw0[nn][dq];
    f32x4 v1 = *(const f32x4*)&Uw0[nn][dq + 4];
    float* dst = out + ((size_t)((1 - p) * 4 + b) * 1024 + n0 + nn) * 256 + h * 32 + dq;
    *(f32x4*)dst = v0;
    *(f32x4*)(dst + 4) = v1;
  }
  {
    f32x4 v0 = *(const f32x4*)&Uw1[nn][dq];
    f32x4 v1 = *(const f32x4*)&Uw1[nn][dq + 4];
    float* dst = out + ((size_t)((1 - p) * 4 + b) * 1024 + n0 + 16 + nn) * 256 + h * 32 + dq;
    *(f32x4*)dst = v0;
    *(f32x4*)(dst + 4) = v1;
  }
}

// ---------------------------------------------------------------------------
extern "C" void kernel_launch(void* const* d_in, const int* in_sizes, int n_in,
                              void* d_out, int out_size, void* d_ws, size_t ws_size,
                              hipStream_t stream) {
  const float* x  = (const float*)d_in[0];
  const float* wr = (const float*)d_in[1];
  const float* wd = (const float*)d_in[2];
  float* out = (float*)d_out;
  char* ws = (char*)d_ws;
  f16* qkvh  = (f16*)(ws + WS_QKVH);
  f16* VT    = (f16*)(ws + WS_VT);
  f16* OT    = (f16*)(ws + WS_OT);
  float* rsums = (float*)(ws + WS_RS);

  k_projm<<<dim3(64, 12), 512, 0, stream>>>(x, wr, wd, qkvh, VT);
  k_fused1<<<dim3(64, 8), 256, 0, stream>>>(qkvh, VT, OT, rsums, out);
  k_fused2<<<dim3(64, 8), 256, 0, stream>>>(qkvh, OT, rsums, out);
}

// Round 10
// 79.175 us; speedup vs baseline: 1.1231x; 1.1231x over previous
//
#include <hip/hip_runtime.h>
#include <cstdint>
#include <cstddef>

// ---------------------------------------------------------------------------
// B=4, N=1024, C=256, H=8, hd=32, ALPHA=0.6
// softmax rows sum to 1 => S_x = attn_x^T; associativity kills the N^3 work.
// r10: r6's proven single-frag math; 64-key/64-q tiles to shrink LDS:
// fused1 51.7KB -> 3 blocks/CU (24 waves/CU), fused2 39.9KB -> 4 blocks/CU
// (32 waves/CU).  r8/r9 lesson: occupancy >> LDS-traffic micro-opts here.
// ---------------------------------------------------------------------------

typedef _Float16 f16;
typedef _Float16 half8 __attribute__((ext_vector_type(8)));
typedef float f32x4 __attribute__((ext_vector_type(4)));

#define ALPHA_F 0.6f
#define OMA_F   0.4f
#define SCALE_L2E 0.25503482f  // (1/sqrt(32)) * log2(e)

static const size_t WS_QKVH = 0;               // 8192*768*2   = 12,582,912
static const size_t WS_VT   = 12582912ull;     // 32*64*1024*2 =  4,194,304
static const size_t WS_OT   = 16777216ull;     // 64*64*1024*2 =  8,388,608
static const size_t WS_RS   = 25165824ull;     // 64*1024*4    =    262,144

__device__ __forceinline__ uint4 pack8(float4 a, float4 b) {
  union { f16 h[8]; uint4 u; } pk;
  pk.h[0] = (f16)a.x; pk.h[1] = (f16)a.y; pk.h[2] = (f16)a.z; pk.h[3] = (f16)a.w;
  pk.h[4] = (f16)b.x; pk.h[5] = (f16)b.y; pk.h[6] = (f16)b.z; pk.h[7] = (f16)b.w;
  return pk.u;
}

// ---------------------------------------------------------------------------
// K1: proj MFMA GEMM, LDS-staged, f32 inputs cast in staging (r7 form).
__global__ __launch_bounds__(512) void k_projm(const float* __restrict__ x,
                                               const float* __restrict__ wr,
                                               const float* __restrict__ wd,
                                               f16* __restrict__ qkvh,
                                               f16* __restrict__ VT) {
  __shared__ f16 Ws[64][264];
  __shared__ f16 Xs[2][128][40];
  __shared__ f16 sc[8][64][24];
  const int t = threadIdx.x;
  const int w = t >> 6, l = t & 63, g = l >> 4, li = l & 15;
  const int m0 = blockIdx.x * 128;
  const int j0 = blockIdx.y * 64;
  const int br = m0 >> 12;
  const int mrow = m0 & 4095;
  const bool qk = (j0 < 512);
  const float* wsrc = br ? wd : wr;
#pragma unroll
  for (int ps = 0; ps < 4; ++ps) {
    const int idx = ps * 512 + t;
    const int wrow = idx >> 5, wc8 = (idx & 31) * 8;
    const float* s = wsrc + (size_t)(j0 + wrow) * 256 + wc8;
    *(uint4*)&Ws[wrow][wc8] = pack8(*(const float4*)s, *(const float4*)(s + 4));
  }
  const int xrow = t >> 2, xc8 = (t & 3) * 8;
  const float* xgl = x + (size_t)(mrow + xrow) * 512 + br * 256 + xc8;
  float4 xr0 = *(const float4*)xgl;
  float4 xr1 = *(const float4*)(xgl + 4);
  *(uint4*)&Xs[0][xrow][xc8] = pack8(xr0, xr1);
  const f32x4 z = {0.f, 0.f, 0.f, 0.f};
  f32x4 c[4] = {z, z, z, z};
  int cur = 0;
  for (int kc = 0; kc < 8; ++kc, cur ^= 1) {
    __syncthreads();
    if (kc < 7) {
      xr0 = *(const float4*)(xgl + (kc + 1) * 32);
      xr1 = *(const float4*)(xgl + (kc + 1) * 32 + 4);
    }
    half8 xa = *(const half8*)&Xs[cur][w * 16 + li][8 * g];
    if (qk) {
#pragma unroll
      for (int jf = 0; jf < 4; ++jf) {
        half8 wa = *(const half8*)&Ws[jf * 16 + li][kc * 32 + 8 * g];
        c[jf] = __builtin_amdgcn_mfma_f32_16x16x32_f16(wa, xa, c[jf], 0, 0, 0);
      }
    } else {
#pragma unroll
      for (int jf = 0; jf < 4; ++jf) {
        half8 wa = *(const half8*)&Ws[jf * 16 + li][kc * 32 + 8 * g];
        c[jf] = __builtin_amdgcn_mfma_f32_16x16x32_f16(xa, wa, c[jf], 0, 0, 0);
      }
    }
    if (kc < 7) *(uint4*)&Xs[cur ^ 1][xrow][xc8] = pack8(xr0, xr1);
  }
  if (qk) {
    f16 (*Qw)[72] = (f16(*)[72])&sc[w][0][0];
#pragma unroll
    for (int jf = 0; jf < 4; ++jf) {
      union { f16 h[4]; uint2 u; } pk;
#pragma unroll
      for (int r = 0; r < 4; ++r) pk.h[r] = (f16)c[jf][r];
      *(uint2*)&Qw[li][jf * 16 + 4 * g] = pk.u;
    }
    const int n = l >> 2, jc = (l & 3) * 16;
    uint4 v0 = *(const uint4*)&Qw[n][jc];
    uint4 v1 = *(const uint4*)&Qw[n][jc + 8];
    f16* dst = qkvh + (size_t)(m0 + w * 16 + n) * 768 + j0 + jc;
    *(uint4*)dst = v0;
    *(uint4*)(dst + 8) = v1;
  } else {
    f16 (*Vw)[24] = (f16(*)[24])&sc[w][0][0];
#pragma unroll
    for (int jf = 0; jf < 4; ++jf) {
      union { f16 h[4]; uint2 u; } pk;
#pragma unroll
      for (int r = 0; r < 4; ++r) pk.h[r] = (f16)c[jf][r];
      *(uint2*)&Vw[jf * 16 + li][4 * g] = pk.u;
    }
    const int jg = j0 + l - 512;
    const int hh = jg >> 5, dd = jg & 31;
    const int b = mrow >> 10;
    const int nn = (mrow & 1023) + w * 16;
    uint4 v0 = *(const uint4*)&Vw[l][0];
    uint4 v1 = *(const uint4*)&Vw[l][8];
    f16* dst = VT + ((size_t)(b * 8 + hh) * 64 + br * 32 + dd) * 1024 + nn;
    *(uint4*)dst = v0;
    *(uint4*)(dst + 8) = v1;
  }
}

// ---------------------------------------------------------------------------
// K2: fused flash pass.  512 thr = 8 waves, wave owns 16 q-rows; 64-key
// tiles, 16 tiles; LDS 51712 B -> 3 blocks/CU.
__global__ __launch_bounds__(512) void k_fused1(const f16* __restrict__ qkvh,
                                                const f16* __restrict__ VT,
                                                f16* __restrict__ OT,
                                                float* __restrict__ rsums,
                                                float* __restrict__ out) {
  __shared__ f16 Ks[2][64][32];    //  8192 B
  __shared__ f16 Vs[2][64][72];    // 18432 B
  __shared__ f16 scw[8][1536];     // 24576 B: P[16][72] / Ow[64][24]
  __shared__ float rsh[8][16];     //   512 B
  const int t = threadIdx.x;
  const int bb = blockIdx.x;
  const int br = bb >> 5, bh = bb & 31, b = bh >> 3, h = bh & 7;
  const int w = t >> 6, l = t & 63, g = l >> 4, li = l & 15;
  const int q0 = blockIdx.y * 128 + w * 16;
  const size_t rowbase = (size_t)(br * 4096 + b * 1024) * 768;
  half8 qf = *(const half8*)(qkvh + rowbase + (size_t)(q0 + li) * 768 + h * 32 + 8 * g);
  // staging: K 64x32 (t<256: 1 uint4), V 64x64 (all t: 1 uint4)
  const int krow = t >> 2, kc8 = (t & 3) * 8;
  const int vrow = t >> 3, vc8 = (t & 7) * 8;
  const f16* kgl = qkvh + rowbase + (size_t)krow * 768 + 256 + h * 32 + kc8;
  const f16* vgl = VT + ((size_t)bh * 64 + vrow) * 1024 + vc8;
  uint4 kreg = {};
  if (t < 256) kreg = *(const uint4*)kgl;
  uint4 vreg = *(const uint4*)vgl;
  if (t < 256) *(uint4*)&Ks[0][krow][kc8] = kreg;
  *(uint4*)&Vs[0][vrow][vc8] = vreg;
  f16 (*P)[72] = (f16(*)[72])&scw[w][0];
  const f32x4 z = {0.f, 0.f, 0.f, 0.f};
  f32x4 o[4] = {z, z, z, z};
  float qsum = 0.f;
  int cur = 0;
  for (int tile = 0; tile < 16; ++tile, cur ^= 1) {
    __syncthreads();
    if (tile < 15) {
      const int m1 = (tile + 1) * 64;
      if (t < 256) kreg = *(const uint4*)(kgl + (size_t)m1 * 768);
      vreg = *(const uint4*)(vgl + m1);
    }
    f32x4 sct[4];
#pragma unroll
    for (int ct = 0; ct < 4; ++ct) {
      half8 ka = *(const half8*)&Ks[cur][ct * 16 + li][8 * g];
      sct[ct] = __builtin_amdgcn_mfma_f32_16x16x32_f16(ka, qf, z, 0, 0, 0);
    }
#pragma unroll
    for (int ct = 0; ct < 4; ++ct) {
      union { f16 hh[4]; uint2 u; } pk;
#pragma unroll
      for (int r = 0; r < 4; ++r) {
        float p = exp2f(sct[ct][r] * SCALE_L2E);
        qsum += p;
        pk.hh[r] = (f16)p;
      }
      *(uint2*)&P[li][ct * 16 + 4 * g] = pk.u;
    }
#pragma unroll
    for (int kk = 0; kk < 2; ++kk) {
      half8 pa = *(const half8*)&P[li][kk * 32 + 8 * g];
#pragma unroll
      for (int jf = 0; jf < 4; ++jf) {
        half8 vv = *(const half8*)&Vs[cur][jf * 16 + li][kk * 32 + 8 * g];
        o[jf] = __builtin_amdgcn_mfma_f32_16x16x32_f16(pa, vv, o[jf], 0, 0, 0);
      }
    }
    if (tile < 15) {
      if (t < 256) *(uint4*)&Ks[cur ^ 1][krow][kc8] = kreg;
      *(uint4*)&Vs[cur ^ 1][vrow][vc8] = vreg;
    }
  }
  qsum += __shfl_xor(qsum, 16, 64);
  qsum += __shfl_xor(qsum, 32, 64);
  const float rinv = 1.0f / qsum;
  if (l < 16) {
    rsh[w][li] = rinv;
    rsums[(size_t)bb * 1024 + q0 + li] = rinv;
  }
  float rv[4];
#pragma unroll
  for (int r = 0; r < 4; ++r) rv[r] = rsh[w][4 * g + r];
#pragma unroll
  for (int jf = 0; jf < 4; ++jf)
#pragma unroll
    for (int r = 0; r < 4; ++r) o[jf][r] *= rv[r];
  // ---- out_r / out_d straight from registers ----
  {
    const int jf0 = br * 2;
    float* obase = out + ((size_t)((2 + br) * 4 + b) * 1024 + q0 + 4 * g) * 256 + h * 32 + li;
#pragma unroll
    for (int jf2 = 0; jf2 < 2; ++jf2)
#pragma unroll
      for (int r = 0; r < 4; ++r)
        obase[(size_t)r * 256 + jf2 * 16] = o[jf0 + jf2][r];
  }
  // ---- transpose O (16q x 64j) -> Ow[j][q] rows [64][24], then OT ----
  f16 (*Ow)[24] = (f16(*)[24])&scw[w][0];
#pragma unroll
  for (int jf = 0; jf < 4; ++jf)
#pragma unroll
    for (int rp = 0; rp < 2; ++rp) {
      union { f16 h[2]; unsigned int u; } pk2;
      pk2.h[0] = (f16)o[jf][2 * rp];
      pk2.h[1] = (f16)o[jf][2 * rp + 1];
      *(unsigned int*)&Ow[jf * 16 + li][4 * g + 2 * rp] = pk2.u;
    }
  {
    uint4 v0 = *(const uint4*)&Ow[l][0];
    uint4 v1 = *(const uint4*)&Ow[l][8];
    f16* dst = OT + ((size_t)bb * 64 + l) * 1024 + q0;
    *(uint4*)dst = v0;
    *(uint4*)(dst + 8) = v1;
  }
}

// ---------------------------------------------------------------------------
// K3: fused recompute + U + combine.  512 thr = 8 waves, wave owns 16
// n-cols; 64-q tiles, 16 tiles; LDS 39936 B -> 4 blocks/CU.
__global__ __launch_bounds__(512) void k_fused2(const f16* __restrict__ qkvh,
                                                const f16* __restrict__ OT,
                                                const float* __restrict__ rsums,
                                                float* __restrict__ out) {
  __shared__ f16 Qs[2][64][32];    //  8192 B
  __shared__ f16 Os[2][32][72];    //  9216 B
  __shared__ f16 sc2h[8][1152];    // 18432 B: P[16][72] / Uw[16][36] f32
  __shared__ float rb[1024];       //  4096 B
  const int t = threadIdx.x;
  const int pb = blockIdx.x;
  const int p = pb >> 5, bh = pb & 31, b = bh >> 3, h = bh & 7;
  const int w = t >> 6, l = t & 63, g = l >> 4, li = l & 15;
  const int n0 = blockIdx.y * 128 + w * 16;
  const int abb = p * 32 + bh;
  const int obb = p ? bh : 32 + bh;
  const int aoff = p ? 0 : 32;
  const size_t rowbase = (size_t)(p * 4096 + b * 1024) * 768;
  rb[t] = rsums[(size_t)abb * 1024 + t];
  rb[t + 512] = rsums[(size_t)abb * 1024 + t + 512];
  half8 kf = *(const half8*)(qkvh + rowbase + (size_t)(n0 + li) * 768 + 256 + h * 32 + 8 * g);
  // staging: Q 64x32 (t<256), O 32x64 (t>=256)
  const int qrow = t >> 2, qc8 = (t & 3) * 8;
  const int t2 = t & 255;
  const int orow = t2 >> 3, oc8 = (t2 & 7) * 8;
  const f16* qgl = qkvh + rowbase + (size_t)qrow * 768 + h * 32 + qc8;
  const f16* ogl = OT + ((size_t)obb * 64 + aoff + orow) * 1024 + oc8;
  uint4 qreg = {}, oreg = {};
  if (t < 256) qreg = *(const uint4*)qgl;
  else oreg = *(const uint4*)ogl;
  if (t < 256) *(uint4*)&Qs[0][qrow][qc8] = qreg;
  else *(uint4*)&Os[0][orow][oc8] = oreg;
  f16 (*P)[72] = (f16(*)[72])&sc2h[w][0];
  const f32x4 z = {0.f, 0.f, 0.f, 0.f};
  f32x4 u0 = z, u1 = z;
  int cur = 0;
  for (int tile = 0; tile < 16; ++tile, cur ^= 1) {
    __syncthreads();
    if (tile < 15) {
      const int q1 = (tile + 1) * 64;
      if (t < 256) qreg = *(const uint4*)(qgl + (size_t)q1 * 768);
      else oreg = *(const uint4*)(ogl + q1);
    }
    const int qt0 = tile * 64;
#pragma unroll
    for (int fq = 0; fq < 4; ++fq) {
      half8 qa = *(const half8*)&Qs[cur][fq * 16 + li][8 * g];
      f32x4 s = __builtin_amdgcn_mfma_f32_16x16x32_f16(qa, kf, z, 0, 0, 0);
      union { f16 hh[4]; uint2 u; } pk;
#pragma unroll
      for (int r = 0; r < 4; ++r)
        pk.hh[r] = (f16)(exp2f(s[r] * SCALE_L2E) * rb[qt0 + fq * 16 + 4 * g + r]);
      *(uint2*)&P[li][fq * 16 + 4 * g] = pk.u;
    }
#pragma unroll
    for (int kk = 0; kk < 2; ++kk) {
      half8 pbf = *(const half8*)&P[li][kk * 32 + 8 * g];
      half8 A0 = *(const half8*)&Os[cur][li][kk * 32 + 8 * g];
      half8 A1 = *(const half8*)&Os[cur][16 + li][kk * 32 + 8 * g];
      u0 = __builtin_amdgcn_mfma_f32_16x16x32_f16(A0, pbf, u0, 0, 0, 0);
      u1 = __builtin_amdgcn_mfma_f32_16x16x32_f16(A1, pbf, u1, 0, 0, 0);
    }
    if (tile < 15) {
      if (t < 256) *(uint4*)&Qs[cur ^ 1][qrow][qc8] = qreg;
      else *(uint4*)&Os[cur ^ 1][orow][oc8] = oreg;
    }
  }
  // combine: alpha*U + 0.4*(OT[bh] + OT[32+bh]) rows aoff+d
  float (*Uw)[36] = (float(*)[36])&sc2h[w][0];
#pragma unroll
  for (int df = 0; df < 2; ++df)
#pragma unroll
    for (int r = 0; r < 4; ++r) {
      const int d_l = df * 16 + 4 * g + r;
      float uu = df ? u1[r] : u0[r];
      float a1 = (float)OT[((size_t)bh * 64 + aoff + d_l) * 1024 + n0 + li];
      float a2 = (float)OT[((size_t)(32 + bh) * 64 + aoff + d_l) * 1024 + n0 + li];
      Uw[li][d_l] = ALPHA_F * uu + OMA_F * (a1 + a2);
    }
  const int nn = l >> 2, dq = (l & 3) * 8;
  f32x4 v0 = *(const f32x4*)&Uw[nn][dq];
  f32x4 v1 = *(const f32x4*)&Uw[nn][dq + 4];
  float* dst = out + ((size_t)((1 - p) * 4 + b) * 1024 + n0 + nn) * 256 + h * 32 + dq;
  *(f32x4*)dst = v0;
  *(f32x4*)(dst + 4) = v1;
}

// ---------------------------------------------------------------------------
extern "C" void kernel_launch(void* const* d_in, const int* in_sizes, int n_in,
                              void* d_out, int out_size, void* d_ws, size_t ws_size,
                              hipStream_t stream) {
  const float* x  = (const float*)d_in[0];
  const float* wr = (const float*)d_in[1];
  const float* wd = (const float*)d_in[2];
  float* out = (float*)d_out;
  char* ws = (char*)d_ws;
  f16* qkvh  = (f16*)(ws + WS_QKVH);
  f16* VT    = (f16*)(ws + WS_VT);
  f16* OT    = (f16*)(ws + WS_OT);
  float* rsums = (float*)(ws + WS_RS);

  k_projm<<<dim3(64, 12), 512, 0, stream>>>(x, wr, wd, qkvh, VT);
  k_fused1<<<dim3(64, 8), 512, 0, stream>>>(qkvh, VT, OT, rsums, out);
  k_fused2<<<dim3(64, 8), 512, 0, stream>>>(qkvh, OT, rsums, out);
}

// Round 11
// 71.112 us; speedup vs baseline: 1.2504x; 1.1134x over previous
//
#include <hip/hip_runtime.h>
#include <cstdint>
#include <cstddef>

// ---------------------------------------------------------------------------
// B=4, N=1024, C=256, H=8, hd=32, ALPHA=0.6
// softmax rows sum to 1 => S_x = attn_x^T; associativity kills the N^3 work.
// r11 = r6 exact (proven 70.3us champion: k_cast + projm-f16 + 128-key-tile
// fused kernels, 2 blocks x 8 waves /CU) + ONE delta: fused2's combine-OT
// reads hoisted to kernel top (issue-early/consume-late) to hide the serial
// global-latency tail. r7-r10 ledger: cast-fold -4us, 1 blk/CU -7, 8 waves
// /CU -19, small-tiles -9 => this structure is the local optimum.
// ---------------------------------------------------------------------------

typedef _Float16 f16;
typedef _Float16 half8 __attribute__((ext_vector_type(8)));
typedef float f32x4 __attribute__((ext_vector_type(4)));

#define ALPHA_F 0.6f
#define OMA_F   0.4f
#define SCALE_F 0.17677669529663687f  // 1/sqrt(32)

static const size_t WS_XH   = 0;            //  4,194,304
static const size_t WS_WH   = 4194304ull;   //    786,432
static const size_t WS_QKVH = 4980736ull;   // 12,582,912
static const size_t WS_VT   = 17563648ull;  //  4,194,304
static const size_t WS_OT   = 21757952ull;  //  8,388,608
static const size_t WS_RS   = 30146560ull;  //    262,144

// ---------------------------------------------------------------------------
// K0: cast x -> xh[2][4096][256], w_r/w_d -> wh[2][768][256].  8 f16/thread.
__global__ __launch_bounds__(256) void k_cast(const float* __restrict__ x,
                                              const float* __restrict__ wr,
                                              const float* __restrict__ wd,
                                              f16* __restrict__ xh,
                                              f16* __restrict__ wh) {
  const int gid = blockIdx.x * 256 + threadIdx.x;
  if (gid < 262144) {
    const int i0 = gid * 8;
    const int k = i0 & 255, row = (i0 >> 8) & 4095, br = i0 >> 20;
    const float* src = x + (size_t)row * 512 + br * 256 + k;
    float4 a = *(const float4*)src;
    float4 b = *(const float4*)(src + 4);
    union { f16 h[8]; uint4 u; } pk;
    pk.h[0] = (f16)a.x; pk.h[1] = (f16)a.y; pk.h[2] = (f16)a.z; pk.h[3] = (f16)a.w;
    pk.h[4] = (f16)b.x; pk.h[5] = (f16)b.y; pk.h[6] = (f16)b.z; pk.h[7] = (f16)b.w;
    *(uint4*)(xh + i0) = pk.u;
  } else {
    const int i0 = (gid - 262144) * 8;
    const int br = (i0 >= 196608) ? 1 : 0;
    const int j = i0 - br * 196608;
    const float* w = br ? wd : wr;
    float4 a = *(const float4*)(w + j);
    float4 b = *(const float4*)(w + j + 4);
    union { f16 h[8]; uint4 u; } pk;
    pk.h[0] = (f16)a.x; pk.h[1] = (f16)a.y; pk.h[2] = (f16)a.z; pk.h[3] = (f16)a.w;
    pk.h[4] = (f16)b.x; pk.h[5] = (f16)b.y; pk.h[6] = (f16)b.z; pk.h[7] = (f16)b.w;
    *(uint4*)(wh + i0) = pk.u;
  }
}

// ---------------------------------------------------------------------------
// K1: proj MFMA GEMM, LDS-staged (r6 form, f16 inputs).
__global__ __launch_bounds__(512) void k_projm(const f16* __restrict__ xh,
                                               const f16* __restrict__ wh,
                                               f16* __restrict__ qkvh,
                                               f16* __restrict__ VT) {
  __shared__ f16 Ws[64][264];
  __shared__ f16 Xs[2][128][32];
  __shared__ f16 sc[8][64][24];
  const int t = threadIdx.x;
  const int w = t >> 6, l = t & 63, g = l >> 4, li = l & 15;
  const int m0 = blockIdx.x * 128;
  const int j0 = blockIdx.y * 64;
  const int br = m0 >> 12;
  const int mrow = m0 & 4095;
  const bool qk = (j0 < 512);
#pragma unroll
  for (int ps = 0; ps < 4; ++ps) {
    const int idx = ps * 512 + t;
    const int wr_ = idx >> 5, wc8 = (idx & 31) * 8;
    uint4 wv = *(const uint4*)(wh + (size_t)(br * 768 + j0 + wr_) * 256 + wc8);
    *(uint4*)&Ws[wr_][wc8] = wv;
  }
  const int xrow = t >> 2, xc8 = (t & 3) * 8;
  const f16* xgl = xh + (size_t)(br * 4096 + mrow + xrow) * 256 + xc8;
  uint4 xreg = *(const uint4*)xgl;
  *(uint4*)&Xs[0][xrow][xc8] = xreg;
  const f32x4 z = {0.f, 0.f, 0.f, 0.f};
  f32x4 c[4] = {z, z, z, z};
  int cur = 0;
  for (int kc = 0; kc < 8; ++kc, cur ^= 1) {
    __syncthreads();
    if (kc < 7) xreg = *(const uint4*)(xgl + (kc + 1) * 32);
    half8 xa = *(const half8*)&Xs[cur][w * 16 + li][8 * g];
    if (qk) {
#pragma unroll
      for (int jf = 0; jf < 4; ++jf) {
        half8 wa = *(const half8*)&Ws[jf * 16 + li][kc * 32 + 8 * g];
        c[jf] = __builtin_amdgcn_mfma_f32_16x16x32_f16(wa, xa, c[jf], 0, 0, 0);
      }
    } else {
#pragma unroll
      for (int jf = 0; jf < 4; ++jf) {
        half8 wa = *(const half8*)&Ws[jf * 16 + li][kc * 32 + 8 * g];
        c[jf] = __builtin_amdgcn_mfma_f32_16x16x32_f16(xa, wa, c[jf], 0, 0, 0);
      }
    }
    if (kc < 7) *(uint4*)&Xs[cur ^ 1][xrow][xc8] = xreg;
  }
  if (qk) {
    f16 (*Qw)[72] = (f16(*)[72])&sc[w][0][0];
#pragma unroll
    for (int jf = 0; jf < 4; ++jf) {
      union { f16 h[4]; uint2 u; } pk;
#pragma unroll
      for (int r = 0; r < 4; ++r) pk.h[r] = (f16)c[jf][r];
      *(uint2*)&Qw[li][jf * 16 + 4 * g] = pk.u;
    }
    const int n = l >> 2, jc = (l & 3) * 16;
    uint4 v0 = *(const uint4*)&Qw[n][jc];
    uint4 v1 = *(const uint4*)&Qw[n][jc + 8];
    f16* dst = qkvh + (size_t)(m0 + w * 16 + n) * 768 + j0 + jc;
    *(uint4*)dst = v0;
    *(uint4*)(dst + 8) = v1;
  } else {
    f16 (*Vw)[24] = (f16(*)[24])&sc[w][0][0];
#pragma unroll
    for (int jf = 0; jf < 4; ++jf) {
      union { f16 h[4]; uint2 u; } pk;
#pragma unroll
      for (int r = 0; r < 4; ++r) pk.h[r] = (f16)c[jf][r];
      *(uint2*)&Vw[jf * 16 + li][4 * g] = pk.u;
    }
    const int jg = j0 + l - 512;
    const int hh = jg >> 5, dd = jg & 31;
    const int b = mrow >> 10;
    const int nn = (mrow & 1023) + w * 16;
    uint4 v0 = *(const uint4*)&Vw[l][0];
    uint4 v1 = *(const uint4*)&Vw[l][8];
    f16* dst = VT + ((size_t)(b * 8 + hh) * 64 + br * 32 + dd) * 1024 + nn;
    *(uint4*)dst = v0;
    *(uint4*)(dst + 8) = v1;
  }
}

// ---------------------------------------------------------------------------
// K2: fused flash pass, LDS-staged (r6 form).  512 thr = 8 waves.
__global__ __launch_bounds__(512) void k_fused1(const f16* __restrict__ qkvh,
                                                const f16* __restrict__ VT,
                                                f16* __restrict__ OT,
                                                float* __restrict__ rsums,
                                                float* __restrict__ out) {
  __shared__ f16 Ks[2][128][32];
  __shared__ f16 Vs[2][64][136];
  __shared__ f16 scw[8][1536];
  __shared__ float rsh[8][16];
  const int t = threadIdx.x;
  const int bb = blockIdx.x;
  const int br = bb >> 5, bh = bb & 31, b = bh >> 3, h = bh & 7;
  const int w = t >> 6, l = t & 63, g = l >> 4, li = l & 15;
  const int q0 = blockIdx.y * 128 + w * 16;
  const size_t rowbase = (size_t)(br * 4096 + b * 1024) * 768;
  half8 qf = *(const half8*)(qkvh + rowbase + (size_t)(q0 + li) * 768 + h * 32 + 8 * g);
  const int krow = t >> 2, kc8 = (t & 3) * 8;
  const int vrow = t >> 3, vc8 = (t & 7) * 8;
  const f16* kgl = qkvh + rowbase + (size_t)krow * 768 + 256 + h * 32 + kc8;
  const f16* vgl = VT + ((size_t)bh * 64 + vrow) * 1024 + vc8;
  uint4 kreg = *(const uint4*)kgl;
  uint4 vreg0 = *(const uint4*)vgl;
  uint4 vreg1 = *(const uint4*)(vgl + 64);
  *(uint4*)&Ks[0][krow][kc8] = kreg;
  *(uint4*)&Vs[0][vrow][vc8] = vreg0;
  *(uint4*)&Vs[0][vrow][64 + vc8] = vreg1;
  f16 (*P)[72] = (f16(*)[72])&scw[w][0];
  const f32x4 z = {0.f, 0.f, 0.f, 0.f};
  f32x4 o[4] = {z, z, z, z};
  float qsum = 0.f;
  int cur = 0;
  for (int tile = 0; tile < 8; ++tile, cur ^= 1) {
    __syncthreads();
    if (tile < 7) {
      const int m1 = (tile + 1) * 128;
      kreg = *(const uint4*)(kgl + (size_t)m1 * 768);
      vreg0 = *(const uint4*)(vgl + m1);
      vreg1 = *(const uint4*)(vgl + m1 + 64);
    }
#pragma unroll
    for (int kh = 0; kh < 2; ++kh) {
      f32x4 sct[4];
#pragma unroll
      for (int ct = 0; ct < 4; ++ct) {
        half8 ka = *(const half8*)&Ks[cur][kh * 64 + ct * 16 + li][8 * g];
        sct[ct] = __builtin_amdgcn_mfma_f32_16x16x32_f16(ka, qf, z, 0, 0, 0);
      }
#pragma unroll
      for (int ct = 0; ct < 4; ++ct) {
        union { f16 hh[4]; uint2 u; } pk;
#pragma unroll
        for (int r = 0; r < 4; ++r) {
          float p = __expf(sct[ct][r] * SCALE_F);
          qsum += p;
          pk.hh[r] = (f16)p;
        }
        *(uint2*)&P[li][ct * 16 + 4 * g] = pk.u;
      }
#pragma unroll
      for (int kk = 0; kk < 2; ++kk) {
        half8 pa = *(const half8*)&P[li][kk * 32 + 8 * g];
#pragma unroll
        for (int jf = 0; jf < 4; ++jf) {
          half8 vv = *(const half8*)&Vs[cur][jf * 16 + li][kh * 64 + kk * 32 + 8 * g];
          o[jf] = __builtin_amdgcn_mfma_f32_16x16x32_f16(pa, vv, o[jf], 0, 0, 0);
        }
      }
    }
    if (tile < 7) {
      *(uint4*)&Ks[cur ^ 1][krow][kc8] = kreg;
      *(uint4*)&Vs[cur ^ 1][vrow][vc8] = vreg0;
      *(uint4*)&Vs[cur ^ 1][vrow][64 + vc8] = vreg1;
    }
  }
  qsum += __shfl_xor(qsum, 16, 64);
  qsum += __shfl_xor(qsum, 32, 64);
  const float rinv = 1.0f / qsum;
  if (l < 16) {
    rsh[w][li] = rinv;
    rsums[(size_t)bb * 1024 + q0 + li] = rinv;
  }
  float rv[4];
#pragma unroll
  for (int r = 0; r < 4; ++r) rv[r] = rsh[w][4 * g + r];
#pragma unroll
  for (int jf = 0; jf < 4; ++jf)
#pragma unroll
    for (int r = 0; r < 4; ++r) o[jf][r] *= rv[r];
  // ---- out_r / out_d straight from registers ----
  {
    const int jf0 = br * 2;
    float* obase = out + ((size_t)((2 + br) * 4 + b) * 1024 + q0 + 4 * g) * 256 + h * 32 + li;
#pragma unroll
    for (int jf2 = 0; jf2 < 2; ++jf2)
#pragma unroll
      for (int r = 0; r < 4; ++r)
        obase[(size_t)r * 256 + jf2 * 16] = o[jf0 + jf2][r];
  }
  // ---- transpose O (16q x 64j) -> Ow[j][q] rows [64][24], then OT ----
  f16 (*Ow)[24] = (f16(*)[24])&scw[w][0];
#pragma unroll
  for (int jf = 0; jf < 4; ++jf)
#pragma unroll
    for (int rp = 0; rp < 2; ++rp) {
      union { f16 h[2]; unsigned int u; } pk2;
      pk2.h[0] = (f16)o[jf][2 * rp];
      pk2.h[1] = (f16)o[jf][2 * rp + 1];
      *(unsigned int*)&Ow[jf * 16 + li][4 * g + 2 * rp] = pk2.u;
    }
  {
    uint4 v0 = *(const uint4*)&Ow[l][0];
    uint4 v1 = *(const uint4*)&Ow[l][8];
    f16* dst = OT + ((size_t)bb * 64 + l) * 1024 + q0;
    *(uint4*)dst = v0;
    *(uint4*)(dst + 8) = v1;
  }
}

// ---------------------------------------------------------------------------
// K3: fused recompute + U + combine (r6 form) + combine-OT prefetch at top.
__global__ __launch_bounds__(512) void k_fused2(const f16* __restrict__ qkvh,
                                                const f16* __restrict__ OT,
                                                const float* __restrict__ rsums,
                                                float* __restrict__ out) {
  __shared__ f16 Qs[2][128][32];
  __shared__ f16 Os[2][32][136];
  __shared__ float sc2[8][1088];
  __shared__ float rb[1024];
  const int t = threadIdx.x;
  const int pb = blockIdx.x;
  const int p = pb >> 5, bh = pb & 31, b = bh >> 3, h = bh & 7;
  const int w = t >> 6, l = t & 63, g = l >> 4, li = l & 15;
  const int n0 = blockIdx.y * 128 + w * 16;
  const int abb = p * 32 + bh;
  const int obb = p ? bh : 32 + bh;
  const int aoff = p ? 0 : 32;
  const size_t rowbase = (size_t)(p * 4096 + b * 1024) * 768;
  rb[t] = rsums[(size_t)abb * 1024 + t];
  rb[t + 512] = rsums[(size_t)abb * 1024 + t + 512];
  half8 kf = *(const half8*)(qkvh + rowbase + (size_t)(n0 + li) * 768 + 256 + h * 32 + 8 * g);
  // ---- prefetch combine OT values (consumed after the main loop) ----
  float a1v[2][4], a2v[2][4];
#pragma unroll
  for (int df = 0; df < 2; ++df)
#pragma unroll
    for (int r = 0; r < 4; ++r) {
      const int d_l = aoff + df * 16 + 4 * g + r;
      a1v[df][r] = (float)OT[((size_t)bh * 64 + d_l) * 1024 + n0 + li];
      a2v[df][r] = (float)OT[((size_t)(32 + bh) * 64 + d_l) * 1024 + n0 + li];
    }
  const int qrow = t >> 2, qc8 = (t & 3) * 8;
  const int orow = t >> 4, oc8 = (t & 15) * 8;
  const f16* qgl = qkvh + rowbase + (size_t)qrow * 768 + h * 32 + qc8;
  const f16* ogl = OT + ((size_t)obb * 64 + aoff + orow) * 1024 + oc8;
  uint4 qreg = *(const uint4*)qgl;
  uint4 oreg = *(const uint4*)ogl;
  *(uint4*)&Qs[0][qrow][qc8] = qreg;
  *(uint4*)&Os[0][orow][oc8] = oreg;
  f16 (*P)[136] = (f16(*)[136])&sc2[w][0];
  const f32x4 z = {0.f, 0.f, 0.f, 0.f};
  f32x4 u0 = z, u1 = z;
  int cur = 0;
  for (int tile = 0; tile < 8; ++tile, cur ^= 1) {
    __syncthreads();
    if (tile < 7) {
      const int q1 = (tile + 1) * 128;
      qreg = *(const uint4*)(qgl + (size_t)q1 * 768);
      oreg = *(const uint4*)(ogl + q1);
    }
    const int qt0 = tile * 128;
#pragma unroll
    for (int fq = 0; fq < 8; ++fq) {
      half8 qa = *(const half8*)&Qs[cur][fq * 16 + li][8 * g];
      f32x4 s = __builtin_amdgcn_mfma_f32_16x16x32_f16(qa, kf, z, 0, 0, 0);
      union { f16 hh[4]; uint2 u; } pk;
#pragma unroll
      for (int r = 0; r < 4; ++r)
        pk.hh[r] = (f16)(__expf(s[r] * SCALE_F) * rb[qt0 + fq * 16 + 4 * g + r]);
      *(uint2*)&P[li][fq * 16 + 4 * g] = pk.u;
    }
#pragma unroll
    for (int kk = 0; kk < 4; ++kk) {
      half8 pbf = *(const half8*)&P[li][kk * 32 + 8 * g];
      half8 A0 = *(const half8*)&Os[cur][li][kk * 32 + 8 * g];
      half8 A1 = *(const half8*)&Os[cur][16 + li][kk * 32 + 8 * g];
      u0 = __builtin_amdgcn_mfma_f32_16x16x32_f16(A0, pbf, u0, 0, 0, 0);
      u1 = __builtin_amdgcn_mfma_f32_16x16x32_f16(A1, pbf, u1, 0, 0, 0);
    }
    if (tile < 7) {
      *(uint4*)&Qs[cur ^ 1][qrow][qc8] = qreg;
      *(uint4*)&Os[cur ^ 1][orow][oc8] = oreg;
    }
  }
  // combine: alpha*U + 0.4*(OT[bh] + OT[32+bh]) rows aoff+d (prefetched)
  float (*Uw)[36] = (float(*)[36])&sc2[w][0];
#pragma unroll
  for (int df = 0; df < 2; ++df)
#pragma unroll
    for (int r = 0; r < 4; ++r) {
      const int d_l = df * 16 + 4 * g + r;
      float uu = df ? u1[r] : u0[r];
      Uw[li][d_l] = ALPHA_F * uu + OMA_F * (a1v[df][r] + a2v[df][r]);
    }
  const int nn = l >> 2, dq = (l & 3) * 8;
  f32x4 v0 = *(const f32x4*)&Uw[nn][dq];
  f32x4 v1 = *(const f32x4*)&Uw[nn][dq + 4];
  float* dst = out + ((size_t)((1 - p) * 4 + b) * 1024 + n0 + nn) * 256 + h * 32 + dq;
  *(f32x4*)dst = v0;
  *(f32x4*)(dst + 4) = v1;
}

// ---------------------------------------------------------------------------
extern "C" void kernel_launch(void* const* d_in, const int* in_sizes, int n_in,
                              void* d_out, int out_size, void* d_ws, size_t ws_size,
                              hipStream_t stream) {
  const float* x  = (const float*)d_in[0];
  const float* wr = (const float*)d_in[1];
  const float* wd = (const float*)d_in[2];
  float* out = (float*)d_out;
  char* ws = (char*)d_ws;
  f16* xh    = (f16*)(ws + WS_XH);
  f16* wh    = (f16*)(ws + WS_WH);
  f16* qkvh  = (f16*)(ws + WS_QKVH);
  f16* VT    = (f16*)(ws + WS_VT);
  f16* OT    = (f16*)(ws + WS_OT);
  float* rsums = (float*)(ws + WS_RS);

  k_cast<<<1216, 256, 0, stream>>>(x, wr, wd, xh, wh);
  k_projm<<<dim3(64, 12), 512, 0, stream>>>(xh, wh, qkvh, VT);
  k_fused1<<<dim3(64, 8), 512, 0, stream>>>(qkvh, VT, OT, rsums, out);
  k_fused2<<<dim3(64, 8), 512, 0, stream>>>(qkvh, OT, rsums, out);
}